// Round 1
// 1146.166 us; speedup vs baseline: 1.1670x; 1.1670x over previous
//
#include <hip/hip_runtime.h>
#include <hip/hip_bf16.h>

typedef __bf16 bvec8 __attribute__((ext_vector_type(8)));
typedef float fvec4 __attribute__((ext_vector_type(4)));

#define E_ 4
#define F_ 16
#define O_ 9
#define B_ 512
#define DIN_ 32
#define H_ 4
#define DK_ 32
#define DH_ 128
#define FINAL_ 17
#define EF_ 64
#define EFO_ 576

// ---------------- transpose+downcast prep: in fp32 [batch][R][C] -> out bf16 [batch][C][R] ----------------
__global__ __launch_bounds__(256) void transpose_k(const float* __restrict__ in,
                                                   __bf16* __restrict__ out, int R, int C) {
  __shared__ float tile[64 * 65];
  int r0 = blockIdx.y * 64, c0 = blockIdx.x * 64;
  const float* src = in + (size_t)blockIdx.z * R * C;
  __bf16* dst = out + (size_t)blockIdx.z * R * C;
  for (int idx = threadIdx.x; idx < 4096; idx += 256) {
    int r = idx >> 6, c = idx & 63;
    if ((r0 + r) < R && (c0 + c) < C)
      tile[r * 65 + c] = src[(size_t)(r0 + r) * C + (c0 + c)];
  }
  __syncthreads();
  for (int idx = threadIdx.x; idx < 4096; idx += 256) {
    int c = idx >> 6, r = idx & 63;
    if ((r0 + r) < R && (c0 + c) < C)
      dst[(size_t)(c0 + c) * R + (r0 + r)] = (__bf16)tile[r * 65 + c];
  }
}

// ---------------- staging helpers ----------------
// LDS tile layout: panels [K/32][128 rows][32 k], fragments read as contiguous 16B.

// Async global->LDS staging (width 16). LDS dest is wave-uniform base + lane*16
// (linear within each 1KB wave-block = 16 rows of one panel); global addr per-lane.
// Requires all 64 lanes active. 8-wave (512-thread) blocks.
__device__ __forceinline__ void stage_async(const __bf16* __restrict__ g, int ldg,
                                            __bf16* s, int cols) {
  int lane = threadIdx.x & 63, w = threadIdx.x >> 6;
  int nwb = cols >> 2;  // wave-blocks: 128 rows * (cols/8) chunks / 64 lanes
  for (int wb = w; wb < nwb; wb += 8) {
    int p = wb >> 3, r0 = (wb & 7) << 4;
    int r = r0 + (lane >> 2), c = lane & 3;
    const __bf16* gp = g + (size_t)r * ldg + p * 32 + c * 8;
    __bf16* lp = s + (((p << 7) + r0) << 5);  // wave-uniform
    __builtin_amdgcn_global_load_lds((const __attribute__((address_space(1))) void*)gp,
                                     (__attribute__((address_space(3))) void*)lp,
                                     16, 0, 0);
  }
}

// fp32 global source -> bf16 LDS tile (VALU path), 512-thread blocks
__device__ __forceinline__ void stage_tile_f32_512(const float* __restrict__ g, int ldg,
                                                   __bf16* s, int cols) {
  int cpr = cols >> 3;
  int nch = 128 * cpr;
  for (int c = threadIdx.x; c < nch; c += 512) {
    int r = c / cpr;
    int cc = (c - r * cpr) << 3;
    const float* gp = g + (size_t)r * ldg + cc;
    float4 f0 = *(const float4*)gp;
    float4 f1 = *(const float4*)(gp + 4);
    bvec8 bv;
    bv[0] = (__bf16)f0.x; bv[1] = (__bf16)f0.y; bv[2] = (__bf16)f0.z; bv[3] = (__bf16)f0.w;
    bv[4] = (__bf16)f1.x; bv[5] = (__bf16)f1.y; bv[6] = (__bf16)f1.z; bv[7] = (__bf16)f1.w;
    *(bvec8*)(s + ((cc >> 5) * 128 + r) * 32 + (cc & 31)) = bv;
  }
}

// legacy 256-thread reg-staging (pred_kernel only)
__device__ __forceinline__ void stage_tile(const __bf16* __restrict__ g, int ldg,
                                           __bf16* s, int cols) {
  int cpr = cols >> 3;
  int nch = 128 * cpr;
  for (int c = threadIdx.x; c < nch; c += 256) {
    int r = c / cpr;
    int cc = (c - r * cpr) << 3;
    *(uint4*)(s + ((cc >> 5) * 128 + r) * 32 + (cc & 31)) =
        *(const uint4*)(g + (size_t)r * ldg + cc);
  }
}

// ---------------- GEMM cores ----------------
// 8-wave version: wave grid 2(M)x4(N), wave tile 64x32, acc[4][2]
__device__ __forceinline__ void gemm128_8(const __bf16* As, const __bf16* Ws, int K,
                                          fvec4 acc[4][2], int wm, int wn, int lm, int q8) {
  for (int k0 = 0; k0 < K; k0 += 32) {
    const __bf16* ap = As + (k0 >> 5) * 4096 + q8;
    const __bf16* bp = Ws + (k0 >> 5) * 4096 + q8;
    bvec8 a[4], b[2];
#pragma unroll
    for (int i = 0; i < 4; i++) a[i] = *(const bvec8*)(ap + (wm + i * 16 + lm) * 32);
#pragma unroll
    for (int j = 0; j < 2; j++) b[j] = *(const bvec8*)(bp + (wn + j * 16 + lm) * 32);
#pragma unroll
    for (int i = 0; i < 4; i++)
#pragma unroll
      for (int j = 0; j < 2; j++)
        acc[i][j] = __builtin_amdgcn_mfma_f32_16x16x32_bf16(a[i], b[j], acc[i][j], 0, 0, 0);
  }
}

// legacy 4-wave version (pred_kernel only): wave grid 2x2, wave tile 64x64, acc[4][4]
__device__ __forceinline__ void gemm128(const __bf16* As, const __bf16* Ws, int K,
                                        fvec4 acc[4][4], int wm, int wn, int lm, int q8) {
  for (int k0 = 0; k0 < K; k0 += 32) {
    const __bf16* ap = As + (k0 >> 5) * 4096 + q8;
    const __bf16* bp = Ws + (k0 >> 5) * 4096 + q8;
    bvec8 a[4], b[4];
#pragma unroll
    for (int i = 0; i < 4; i++) a[i] = *(const bvec8*)(ap + (wm + i * 16 + lm) * 32);
#pragma unroll
    for (int j = 0; j < 4; j++) b[j] = *(const bvec8*)(bp + (wn + j * 16 + lm) * 32);
#pragma unroll
    for (int i = 0; i < 4; i++)
#pragma unroll
      for (int j = 0; j < 4; j++)
        acc[i][j] = __builtin_amdgcn_mfma_f32_16x16x32_bf16(a[i], b[j], acc[i][j], 0, 0, 0);
  }
}

// ---------------- K1: fused 2-layer per-object MLP (512 threads) ----------------
__global__ __launch_bounds__(512) void mlp_kernel(const float* __restrict__ x,
    const __bf16* __restrict__ fw1t, const float* __restrict__ fb1,
    const __bf16* __restrict__ fw2t, const float* __restrict__ fb2,
    __bf16* __restrict__ h0) {
  __shared__ __align__(16) __bf16 smem[32768];
  int efo = blockIdx.y, mt = blockIdx.x;
  int t = threadIdx.x, l = t & 63, w = t >> 6;
  int wm = (w & 1) * 64, wn = (w >> 1) * 32;
  int lm = l & 15, q8 = (l >> 4) * 8, qr = (l >> 4) * 4;
  __bf16* xs = smem;           // [1][128][32] = 4096
  __bf16* w1s = smem + 4096;   // 4096
  __bf16* h1s = smem;          // phase 2: [4][128][32] = 16384
  __bf16* w2s = smem + 16384;  // 16384 (disjoint from phase-1 regions)
  // stage phase-2 weight asynchronously up front (no region overlap)
  stage_async(fw2t + (size_t)efo * DH_ * DH_, DH_, w2s, DH_);
  stage_async(fw1t + (size_t)efo * DH_ * DIN_, DIN_, w1s, DIN_);
  stage_tile_f32_512(x + ((size_t)efo * B_ + mt * 128) * DIN_, DIN_, xs, DIN_);
  __syncthreads();
  fvec4 zero4 = {0.f, 0.f, 0.f, 0.f};
  fvec4 acc[4][2];
#pragma unroll
  for (int i = 0; i < 4; i++)
#pragma unroll
    for (int j = 0; j < 2; j++) acc[i][j] = zero4;
  gemm128_8(xs, w1s, 32, acc, wm, wn, lm, q8);
  __syncthreads();  // all waves done reading xs/w1s
  float bias[2];
#pragma unroll
  for (int j = 0; j < 2; j++) bias[j] = fb1[efo * DH_ + wn + j * 16 + lm];
#pragma unroll
  for (int i = 0; i < 4; i++)
#pragma unroll
    for (int j = 0; j < 2; j++)
#pragma unroll
      for (int r = 0; r < 4; r++) {
        float v = fmaxf(acc[i][j][r] + bias[j], 0.f);
        int row = wm + i * 16 + qr + r, col = wn + j * 16 + lm;
        h1s[((col >> 5) * 128 + row) * 32 + (col & 31)] = (__bf16)v;
      }
  __syncthreads();
#pragma unroll
  for (int i = 0; i < 4; i++)
#pragma unroll
    for (int j = 0; j < 2; j++) acc[i][j] = zero4;
  gemm128_8(h1s, w2s, 128, acc, wm, wn, lm, q8);
#pragma unroll
  for (int j = 0; j < 2; j++) bias[j] = fb2[efo * DH_ + wn + j * 16 + lm];
#pragma unroll
  for (int i = 0; i < 4; i++)
#pragma unroll
    for (int j = 0; j < 2; j++)
#pragma unroll
      for (int r = 0; r < 4; r++) {
        float v = fmaxf(acc[i][j][r] + bias[j], 0.f);
        int row = wm + i * 16 + qr + r, col = wn + j * 16 + lm;
        h0[((size_t)efo * B_ + mt * 128 + row) * DH_ + col] = (__bf16)v;
      }
}

// ---------------- K2: fused q+k head-projection (512 threads) ----------------
// Stages h once; computes q then k; k-weight staged async while q stores drain.
__global__ __launch_bounds__(512) void qk_kernel(const __bf16* __restrict__ hsrc,
    const __bf16* __restrict__ wqt, const __bf16* __restrict__ wkt,
    __bf16* __restrict__ qdst, __bf16* __restrict__ kdst) {
  __shared__ __align__(16) __bf16 smem[32768];
  int efo = blockIdx.y, mt = blockIdx.x;
  int ef = efo / O_, o = efo - ef * O_;
  int t = threadIdx.x, l = t & 63, w = t >> 6;
  int wm = (w & 1) * 64, wn = (w >> 1) * 32;
  int lm = l & 15, q8 = (l >> 4) * 8, qr = (l >> 4) * 4;
  __bf16* hs = smem;
  __bf16* wsm = smem + 16384;
  stage_async(hsrc + ((size_t)efo * B_ + mt * 128) * DH_, DH_, hs, DH_);
  stage_async(wqt + (size_t)efo * DH_ * DH_, DH_, wsm, DH_);
  __syncthreads();
  fvec4 zero4 = {0.f, 0.f, 0.f, 0.f};
  fvec4 acc[4][2];
#pragma unroll
  for (int i = 0; i < 4; i++)
#pragma unroll
    for (int j = 0; j < 2; j++) acc[i][j] = zero4;
  gemm128_8(hs, wsm, 128, acc, wm, wn, lm, q8);
  __syncthreads();  // all waves done reading wq
  stage_async(wkt + (size_t)efo * DH_ * DH_, DH_, wsm, DH_);  // in flight during q store
#pragma unroll
  for (int i = 0; i < 4; i++)
#pragma unroll
    for (int j = 0; j < 2; j++)
#pragma unroll
      for (int r = 0; r < 4; r++) {
        int row = wm + i * 16 + qr + r, col = wn + j * 16 + lm;
        int hh = col >> 5, d = col & 31, b = mt * 128 + row;
        qdst[((((size_t)ef * H_ + hh) * O_ + o) * B_ + b) * DK_ + d] =
            (__bf16)acc[i][j][r];
        acc[i][j][r] = 0.f;
      }
  __syncthreads();  // drains wk loads
  gemm128_8(hs, wsm, 128, acc, wm, wn, lm, q8);
#pragma unroll
  for (int i = 0; i < 4; i++)
#pragma unroll
    for (int j = 0; j < 2; j++)
#pragma unroll
      for (int r = 0; r < 4; r++) {
        int row = wm + i * 16 + qr + r, col = wn + j * 16 + lm;
        int hh = col >> 5, d = col & 31, b = mt * 128 + row;
        kdst[((((size_t)ef * H_ + hh) * O_ + o) * B_ + b) * DK_ + d] =
            (__bf16)acc[i][j][r];
      }
}

// ---------------- K2b: single head-projection GEMM (v) (512 threads) ----------------
__global__ __launch_bounds__(512) void headproj_kernel(const __bf16* __restrict__ hsrc,
    const __bf16* __restrict__ wt, __bf16* __restrict__ dst) {
  __shared__ __align__(16) __bf16 smem[32768];
  int efo = blockIdx.y, mt = blockIdx.x;
  int ef = efo / O_, o = efo - ef * O_;
  int t = threadIdx.x, l = t & 63, w = t >> 6;
  int wm = (w & 1) * 64, wn = (w >> 1) * 32;
  int lm = l & 15, q8 = (l >> 4) * 8, qr = (l >> 4) * 4;
  __bf16* hs = smem;
  __bf16* wsm = smem + 16384;
  stage_async(hsrc + ((size_t)efo * B_ + mt * 128) * DH_, DH_, hs, DH_);
  stage_async(wt + (size_t)efo * DH_ * DH_, DH_, wsm, DH_);
  __syncthreads();
  fvec4 zero4 = {0.f, 0.f, 0.f, 0.f};
  fvec4 acc[4][2];
#pragma unroll
  for (int i = 0; i < 4; i++)
#pragma unroll
    for (int j = 0; j < 2; j++) acc[i][j] = zero4;
  gemm128_8(hs, wsm, 128, acc, wm, wn, lm, q8);
#pragma unroll
  for (int i = 0; i < 4; i++)
#pragma unroll
    for (int j = 0; j < 2; j++)
#pragma unroll
      for (int r = 0; r < 4; r++) {
        int row = wm + i * 16 + qr + r, col = wn + j * 16 + lm;
        int hh = col >> 5, d = col & 31, b = mt * 128 + row;
        dst[((((size_t)ef * H_ + hh) * O_ + o) * B_ + b) * DK_ + d] =
            (__bf16)acc[i][j][r];
      }
}

// ---------------- K3: scores + softmax -> P (normalized, bf16) ----------------
__global__ __launch_bounds__(256) void score_kernel(const __bf16* __restrict__ q,
    const __bf16* __restrict__ k, __bf16* __restrict__ P) {
  int t = threadIdx.x;
  int g = t >> 2, sub = t & 3;
  int blk = blockIdx.x;
  int bt = blk & 7, efh = blk >> 3;
  int b = bt * 64 + g, d0 = sub * 8;
  size_t base = (size_t)efh * O_ * B_ * DK_ + (size_t)b * DK_ + d0;
  const size_t ostr = (size_t)B_ * DK_;
  bvec8 kr[9];
#pragma unroll
  for (int o = 0; o < 9; o++) kr[o] = *(const bvec8*)(k + base + (size_t)o * ostr);
  const float scale = 0.17677669529663687f;  // 1/sqrt(32)
  size_t pbase = ((size_t)efh * B_ + b) * 81;
#pragma unroll 1
  for (int oq = 0; oq < 9; oq++) {
    bvec8 qv = *(const bvec8*)(q + base + (size_t)oq * ostr);
    float qf[8];
#pragma unroll
    for (int j = 0; j < 8; j++) qf[j] = (float)qv[j];
    float lg[9];
#pragma unroll
    for (int ok = 0; ok < 9; ok++) {
      float s = 0.f;
#pragma unroll
      for (int j = 0; j < 8; j++) s += qf[j] * (float)kr[ok][j];
      s += __shfl_xor(s, 1);
      s += __shfl_xor(s, 2);
      lg[ok] = s * scale;
    }
    float mx = lg[0];
#pragma unroll
    for (int ok = 1; ok < 9; ok++) mx = fmaxf(mx, lg[ok]);
    float sum = 0.f;
#pragma unroll
    for (int ok = 0; ok < 9; ok++) { lg[ok] = __expf(lg[ok] - mx); sum += lg[ok]; }
    float inv = 1.f / sum;
    for (int ok = sub; ok < 9; ok += 4)
      P[pbase + oq * 9 + ok] = (__bf16)(lg[ok] * inv);
  }
}

// ---------------- K4: apply P to V ----------------
__global__ __launch_bounds__(256) void apply_kernel(const __bf16* __restrict__ P,
    const __bf16* __restrict__ v, __bf16* __restrict__ a) {
  int t = threadIdx.x;
  int g = t >> 2, sub = t & 3;
  int blk = blockIdx.x;
  int bt = blk & 7, efh = blk >> 3;
  int b = bt * 64 + g, d0 = sub * 8;
  size_t base = (size_t)efh * O_ * B_ * DK_ + (size_t)b * DK_ + d0;
  const size_t ostr = (size_t)B_ * DK_;
  bvec8 vr[9];
#pragma unroll
  for (int o = 0; o < 9; o++) vr[o] = *(const bvec8*)(v + base + (size_t)o * ostr);
  size_t pbase = ((size_t)efh * B_ + b) * 81;
#pragma unroll 1
  for (int oq = 0; oq < 9; oq++) {
    float pw[9];
#pragma unroll
    for (int ok = 0; ok < 9; ok++) pw[ok] = (float)P[pbase + oq * 9 + ok];
    float oacc[8] = {0.f, 0.f, 0.f, 0.f, 0.f, 0.f, 0.f, 0.f};
#pragma unroll
    for (int ok = 0; ok < 9; ok++)
#pragma unroll
      for (int j = 0; j < 8; j++) oacc[j] += pw[ok] * (float)vr[ok][j];
    bvec8 ov;
#pragma unroll
    for (int j = 0; j < 8; j++) ov[j] = (__bf16)oacc[j];
    *(bvec8*)(a + base + (size_t)oq * ostr) = ov;
  }
}

// ---------------- K5: out-proj + residual + post-FC (512 threads; hout may alias resid) ----------------
__global__ __launch_bounds__(512) void proj_kernel(const __bf16* __restrict__ ain,
    const __bf16* __restrict__ wot, const __bf16* __restrict__ pwt,
    const float* __restrict__ pb, const __bf16* resid,
    __bf16* hout) {
  __shared__ __align__(16) __bf16 smem[32768];
  int efo = blockIdx.y, mt = blockIdx.x;
  int ef = efo / O_, o = efo - ef * O_;
  int t = threadIdx.x, l = t & 63, w = t >> 6;
  int wm = (w & 1) * 64, wn = (w >> 1) * 32;
  int lm = l & 15, q8 = (l >> 4) * 8, qr = (l >> 4) * 4;
  __bf16* as2 = smem;
  __bf16* wsm = smem + 16384;
#pragma unroll
  for (int hh = 0; hh < 4; hh++)
    stage_async(ain + ((((size_t)ef * H_ + hh) * O_ + o) * B_ + mt * 128) * DK_, DK_,
                as2 + hh * 4096, DK_);
  stage_async(wot + (size_t)efo * DH_ * DH_, DH_, wsm, DH_);
  __syncthreads();
  fvec4 zero4 = {0.f, 0.f, 0.f, 0.f};
  fvec4 acc[4][2];
#pragma unroll
  for (int i = 0; i < 4; i++)
#pragma unroll
    for (int j = 0; j < 2; j++) acc[i][j] = zero4;
  gemm128_8(as2, wsm, 128, acc, wm, wn, lm, q8);
  // residual add (fp32); tile is block-private and read-before-write per thread,
  // so in-place hout==resid is safe
#pragma unroll
  for (int i = 0; i < 4; i++)
#pragma unroll
    for (int j = 0; j < 2; j++)
#pragma unroll
      for (int r = 0; r < 4; r++) {
        int row = wm + i * 16 + qr + r, col = wn + j * 16 + lm;
        acc[i][j][r] +=
            (float)resid[((size_t)efo * B_ + mt * 128 + row) * DH_ + col];
      }
  __syncthreads();  // all waves done reading as2/wot
  stage_async(pwt + (size_t)efo * DH_ * DH_, DH_, wsm, DH_);  // overlaps LDS writeback
#pragma unroll
  for (int i = 0; i < 4; i++)
#pragma unroll
    for (int j = 0; j < 2; j++)
#pragma unroll
      for (int r = 0; r < 4; r++) {
        int row = wm + i * 16 + qr + r, col = wn + j * 16 + lm;
        as2[((col >> 5) * 128 + row) * 32 + (col & 31)] = (__bf16)acc[i][j][r];
      }
  __syncthreads();
#pragma unroll
  for (int i = 0; i < 4; i++)
#pragma unroll
    for (int j = 0; j < 2; j++) acc[i][j] = zero4;
  gemm128_8(as2, wsm, 128, acc, wm, wn, lm, q8);
  float bias[2];
#pragma unroll
  for (int j = 0; j < 2; j++) bias[j] = pb[efo * DH_ + wn + j * 16 + lm];
#pragma unroll
  for (int i = 0; i < 4; i++)
#pragma unroll
    for (int j = 0; j < 2; j++)
#pragma unroll
      for (int r = 0; r < 4; r++) {
        float vv = fmaxf(acc[i][j][r] + bias[j], 0.f);
        int row = wm + i * 16 + qr + r, col = wn + j * 16 + lm;
        hout[((size_t)efo * B_ + mt * 128 + row) * DH_ + col] = (__bf16)vv;
      }
}

// ---------------- K6: mean-pool over objects ----------------
__global__ __launch_bounds__(256) void pool_kernel(const __bf16* __restrict__ h2,
                                                   __bf16* __restrict__ pooled) {
  size_t idx = ((size_t)blockIdx.x * 256 + threadIdx.x) * 8;
  int ef = (int)(idx >> 16);  // B_*DH_ = 65536 per (e,f)
  int rem = (int)(idx & 65535);
  float accv[8] = {0.f, 0.f, 0.f, 0.f, 0.f, 0.f, 0.f, 0.f};
#pragma unroll
  for (int o = 0; o < 9; o++) {
    bvec8 tv = *(const bvec8*)(h2 + (size_t)(ef * O_ + o) * B_ * DH_ + rem);
#pragma unroll
    for (int j = 0; j < 8; j++) accv[j] += (float)tv[j];
  }
  const float inv9 = 1.f / 9.f;
  bvec8 ov;
#pragma unroll
  for (int j = 0; j < 8; j++) ov[j] = (__bf16)(accv[j] * inv9);
  *(bvec8*)(pooled + idx) = ov;
}

// ---------------- K7: predictor (2 GEMMs fused), fp32 output (256 threads) ----------------
__global__ __launch_bounds__(256) void pred_kernel(const __bf16* __restrict__ pooled,
    const __bf16* __restrict__ pw1t, const float* __restrict__ pb1,
    const __bf16* __restrict__ pw2t, const float* __restrict__ pb2,
    float* __restrict__ out) {
  __shared__ __align__(16) __bf16 smem[32768];
  int ef = blockIdx.y, mt = blockIdx.x;
  int t = threadIdx.x, l = t & 63, w = t >> 6;
  int wm = (w & 1) * 64, wn = (w >> 1) * 64;
  int lm = l & 15, q8 = (l >> 4) * 8, qr = (l >> 4) * 4;
  __bf16* ps = smem;
  __bf16* wsm = smem + 16384;
  stage_tile(pooled + ((size_t)ef * B_ + mt * 128) * DH_, DH_, ps, DH_);
  stage_tile(pw1t + (size_t)ef * DH_ * DH_, DH_, wsm, DH_);
  __syncthreads();
  fvec4 zero4 = {0.f, 0.f, 0.f, 0.f};
  fvec4 acc[4][4];
#pragma unroll
  for (int i = 0; i < 4; i++)
#pragma unroll
    for (int j = 0; j < 4; j++) acc[i][j] = zero4;
  gemm128(ps, wsm, 128, acc, wm, wn, lm, q8);
  __syncthreads();
  float bias[4];
#pragma unroll
  for (int j = 0; j < 4; j++) bias[j] = pb1[ef * DH_ + wn + j * 16 + lm];
#pragma unroll
  for (int i = 0; i < 4; i++)
#pragma unroll
    for (int j = 0; j < 4; j++)
#pragma unroll
      for (int r = 0; r < 4; r++) {
        float vv = fmaxf(acc[i][j][r] + bias[j], 0.f);
        int row = wm + i * 16 + qr + r, col = wn + j * 16 + lm;
        ps[((col >> 5) * 128 + row) * 32 + (col & 31)] = (__bf16)vv;
      }
  // stage pw2t [17][128] (bf16, transposed) zero-padded to [32][128]
  for (int c = threadIdx.x; c < 512; c += 256) {
    int r = c >> 4, cc = (c & 15) << 3;
    uint4 val;
    val.x = val.y = val.z = val.w = 0u;
    if (r < FINAL_)
      val = *(const uint4*)(pw2t + (size_t)ef * FINAL_ * DH_ + r * DH_ + cc);
    *(uint4*)(wsm + ((cc >> 5) * 32 + r) * 32 + (cc & 31)) = val;
  }
  __syncthreads();
  fvec4 acc2[2][2];
#pragma unroll
  for (int i = 0; i < 2; i++)
#pragma unroll
    for (int j = 0; j < 2; j++) acc2[i][j] = zero4;
  for (int k0 = 0; k0 < 128; k0 += 32) {
    bvec8 a2[2], b2[2];
#pragma unroll
    for (int i = 0; i < 2; i++)
      a2[i] = *(const bvec8*)(ps + ((k0 >> 5) * 128 + w * 32 + i * 16 + lm) * 32 + q8);
#pragma unroll
    for (int j = 0; j < 2; j++)
      b2[j] = *(const bvec8*)(wsm + ((k0 >> 5) * 32 + j * 16 + lm) * 32 + q8);
#pragma unroll
    for (int i = 0; i < 2; i++)
#pragma unroll
      for (int j = 0; j < 2; j++)
        acc2[i][j] = __builtin_amdgcn_mfma_f32_16x16x32_bf16(a2[i], b2[j], acc2[i][j], 0, 0, 0);
  }
#pragma unroll
  for (int i = 0; i < 2; i++)
#pragma unroll
    for (int j = 0; j < 2; j++)
#pragma unroll
      for (int r = 0; r < 4; r++) {
        int col = j * 16 + lm;
        if (col < FINAL_) {
          int b = mt * 128 + w * 32 + i * 16 + qr + r;
          out[((size_t)ef * B_ + b) * FINAL_ + col] =
              acc2[i][j][r] + pb2[ef * FINAL_ + col];
        }
      }
}

// ---------------- host ----------------
extern "C" void kernel_launch(void* const* d_in, const int* in_sizes, int n_in,
                              void* d_out, int out_size, void* d_ws, size_t ws_size,
                              hipStream_t stream) {
  (void)in_sizes; (void)n_in; (void)out_size; (void)ws_size;
  const float* x     = (const float*)d_in[0];
  const float* fb1   = (const float*)d_in[2];
  const float* fb2   = (const float*)d_in[4];
  const float* a0_pb = (const float*)d_in[10];
  const float* a1_pb = (const float*)d_in[16];
  const float* pb1   = (const float*)d_in[18];
  const float* pb2   = (const float*)d_in[20];

  __bf16* wsb = (__bf16*)d_ws;
  const size_t SLOT = (size_t)EFO_ * DH_ * DH_;   // 9,437,184 elems
  const size_t ABUF = (size_t)EFO_ * B_ * DH_;    // 37,748,736 elems
  __bf16* s0 = wsb;
  __bf16* s1 = s0 + SLOT;
  __bf16* s2 = s1 + SLOT;
  __bf16* A0 = s2 + SLOT;       // h (in-place through both attention blocks)
  __bf16* A1 = A0 + ABUF;       // q, then v
  __bf16* A2 = A1 + ABUF;       // k, then attn-out
  __bf16* Pb = A2 + ABUF;       // [EF*H][B][81] bf16 = 21 MB
  // total: 3*SLOT + 3*ABUF + 10,616,832 elems = ~290 MiB

  auto T = [&](const void* src, __bf16* dst, int R, int C, int batch) {
    dim3 g((C + 63) / 64, (R + 63) / 64, batch);
    transpose_k<<<g, 256, 0, stream>>>((const float*)src, dst, R, C);
  };

  dim3 gg(4, EFO_);

  // MLP
  T(d_in[1], s0, DIN_, DH_, EFO_);
  T(d_in[3], s1, DH_, DH_, EFO_);
  mlp_kernel<<<gg, 512, 0, stream>>>(x, s0, fb1, s1, fb2, A0);

  for (int blkI = 0; blkI < 2; blkI++) {
    int wbase = blkI == 0 ? 5 : 11;
    const float* pb = blkI == 0 ? a0_pb : a1_pb;
    T(d_in[wbase + 0], s0, DH_, DH_, EFO_);  // wq
    T(d_in[wbase + 1], s1, DH_, DH_, EFO_);  // wk
    T(d_in[wbase + 2], s2, DH_, DH_, EFO_);  // wv
    qk_kernel<<<gg, 512, 0, stream>>>(A0, s0, s1, A1, A2);      // q, k
    score_kernel<<<2048, 256, 0, stream>>>(A1, A2, Pb);         // P
    headproj_kernel<<<gg, 512, 0, stream>>>(A0, s2, A1);        // v (over q)
    apply_kernel<<<2048, 256, 0, stream>>>(Pb, A1, A2);         // attn-out (over k)
    T(d_in[wbase + 3], s0, DH_, DH_, EFO_);  // wo
    T(d_in[wbase + 4], s1, DH_, DH_, EFO_);  // pw
    proj_kernel<<<gg, 512, 0, stream>>>(A2, s0, s1, pb, A0, A0);  // in-place h
  }

  // pool + predictor
  T(d_in[17], s0, DH_, DH_, EF_);
  T(d_in[19], s1, DH_, FINAL_, EF_);
  pool_kernel<<<2048, 256, 0, stream>>>(A0, s2);
  pred_kernel<<<dim3(4, EF_), 256, 0, stream>>>(s2, s0, pb1, s1, pb2,
                                                (float*)d_out);
}

// Round 2
// 1013.799 us; speedup vs baseline: 1.3194x; 1.1306x over previous
//
#include <hip/hip_runtime.h>
#include <hip/hip_bf16.h>

typedef __bf16 bvec8 __attribute__((ext_vector_type(8)));
typedef __bf16 bvec4 __attribute__((ext_vector_type(4)));
typedef float fvec4 __attribute__((ext_vector_type(4)));

#define E_ 4
#define F_ 16
#define O_ 9
#define B_ 512
#define DIN_ 32
#define H_ 4
#define DK_ 32
#define DH_ 128
#define FINAL_ 17
#define EF_ 64
#define EFO_ 576

// ---------------- transpose+downcast prep: in fp32 [batch][R][C] -> out bf16 [batch][C][R] ----------------
__global__ __launch_bounds__(256) void transpose_k(const float* __restrict__ in,
                                                   __bf16* __restrict__ out, int R, int C) {
  __shared__ float tile[64 * 65];
  int r0 = blockIdx.y * 64, c0 = blockIdx.x * 64;
  const float* src = in + (size_t)blockIdx.z * R * C;
  __bf16* dst = out + (size_t)blockIdx.z * R * C;
  for (int idx = threadIdx.x; idx < 4096; idx += 256) {
    int r = idx >> 6, c = idx & 63;
    if ((r0 + r) < R && (c0 + c) < C)
      tile[r * 65 + c] = src[(size_t)(r0 + r) * C + (c0 + c)];
  }
  __syncthreads();
  for (int idx = threadIdx.x; idx < 4096; idx += 256) {
    int c = idx >> 6, r = idx & 63;
    if ((r0 + r) < R && (c0 + c) < C)
      dst[(size_t)(c0 + c) * R + (r0 + r)] = (__bf16)tile[r * 65 + c];
  }
}

// batched 128x128 transposes (3 weights / 2 weights in one launch)
__global__ __launch_bounds__(256) void transpose3_k(const float* __restrict__ i0,
    const float* __restrict__ i1, const float* __restrict__ i2,
    __bf16* __restrict__ o0, __bf16* __restrict__ o1, __bf16* __restrict__ o2) {
  __shared__ float tile[64 * 65];
  int z = blockIdx.z;
  int which = z / EFO_, zb = z - which * EFO_;
  const float* in = which == 0 ? i0 : (which == 1 ? i1 : i2);
  __bf16* out = which == 0 ? o0 : (which == 1 ? o1 : o2);
  int r0 = blockIdx.y * 64, c0 = blockIdx.x * 64;
  const float* src = in + (size_t)zb * DH_ * DH_;
  __bf16* dst = out + (size_t)zb * DH_ * DH_;
  for (int idx = threadIdx.x; idx < 4096; idx += 256) {
    int r = idx >> 6, c = idx & 63;
    tile[r * 65 + c] = src[(size_t)(r0 + r) * DH_ + (c0 + c)];
  }
  __syncthreads();
  for (int idx = threadIdx.x; idx < 4096; idx += 256) {
    int c = idx >> 6, r = idx & 63;
    dst[(size_t)(c0 + c) * DH_ + (r0 + r)] = (__bf16)tile[r * 65 + c];
  }
}

__global__ __launch_bounds__(256) void transpose2_k(const float* __restrict__ i0,
    const float* __restrict__ i1, __bf16* __restrict__ o0, __bf16* __restrict__ o1) {
  __shared__ float tile[64 * 65];
  int z = blockIdx.z;
  int which = z / EFO_, zb = z - which * EFO_;
  const float* in = which == 0 ? i0 : i1;
  __bf16* out = which == 0 ? o0 : o1;
  int r0 = blockIdx.y * 64, c0 = blockIdx.x * 64;
  const float* src = in + (size_t)zb * DH_ * DH_;
  __bf16* dst = out + (size_t)zb * DH_ * DH_;
  for (int idx = threadIdx.x; idx < 4096; idx += 256) {
    int r = idx >> 6, c = idx & 63;
    tile[r * 65 + c] = src[(size_t)(r0 + r) * DH_ + (c0 + c)];
  }
  __syncthreads();
  for (int idx = threadIdx.x; idx < 4096; idx += 256) {
    int c = idx >> 6, r = idx & 63;
    dst[(size_t)(c0 + c) * DH_ + (r0 + r)] = (__bf16)tile[r * 65 + c];
  }
}

// ---------------- staging helpers ----------------
// LDS tile layout: panels [K/32][128 rows][32 k], fragments read as contiguous 16B.

// Async global->LDS staging (width 16). LDS dest is wave-uniform base + lane*16;
// global addr per-lane. 8-wave (512-thread) blocks, all lanes active.
__device__ __forceinline__ void stage_async(const __bf16* __restrict__ g, int ldg,
                                            __bf16* s, int cols) {
  int lane = threadIdx.x & 63, w = threadIdx.x >> 6;
  int nwb = cols >> 2;  // wave-blocks of 1KB
  for (int wb = w; wb < nwb; wb += 8) {
    int p = wb >> 3, r0 = (wb & 7) << 4;
    int r = r0 + (lane >> 2), c = lane & 3;
    const __bf16* gp = g + (size_t)r * ldg + p * 32 + c * 8;
    __bf16* lp = s + (((p << 7) + r0) << 5);  // wave-uniform
    __builtin_amdgcn_global_load_lds((const __attribute__((address_space(1))) void*)gp,
                                     (__attribute__((address_space(3))) void*)lp,
                                     16, 0, 0);
  }
}

// fp32 global source -> bf16 LDS tile (VALU path), 512-thread blocks
__device__ __forceinline__ void stage_tile_f32_512(const float* __restrict__ g, int ldg,
                                                   __bf16* s, int cols) {
  int cpr = cols >> 3;
  int nch = 128 * cpr;
  for (int c = threadIdx.x; c < nch; c += 512) {
    int r = c / cpr;
    int cc = (c - r * cpr) << 3;
    const float* gp = g + (size_t)r * ldg + cc;
    float4 f0 = *(const float4*)gp;
    float4 f1 = *(const float4*)(gp + 4);
    bvec8 bv;
    bv[0] = (__bf16)f0.x; bv[1] = (__bf16)f0.y; bv[2] = (__bf16)f0.z; bv[3] = (__bf16)f0.w;
    bv[4] = (__bf16)f1.x; bv[5] = (__bf16)f1.y; bv[6] = (__bf16)f1.z; bv[7] = (__bf16)f1.w;
    *(bvec8*)(s + ((cc >> 5) * 128 + r) * 32 + (cc & 31)) = bv;
  }
}

// legacy 256-thread reg-staging (pred_kernel only)
__device__ __forceinline__ void stage_tile(const __bf16* __restrict__ g, int ldg,
                                           __bf16* s, int cols) {
  int cpr = cols >> 3;
  int nch = 128 * cpr;
  for (int c = threadIdx.x; c < nch; c += 256) {
    int r = c / cpr;
    int cc = (c - r * cpr) << 3;
    *(uint4*)(s + ((cc >> 5) * 128 + r) * 32 + (cc & 31)) =
        *(const uint4*)(g + (size_t)r * ldg + cc);
  }
}

// ---------------- GEMM cores ----------------
// 8-wave, SWAPPED convention: first operand = M (weight cols), second = N (batch rows).
// acc[i][j]: D[Ms_row][Ns_row]; store row index = wm + i*16 + qr + r (Ms), col = wn + j*16 + lm (Ns).
__device__ __forceinline__ void gemm128_8(const __bf16* Ms, const __bf16* Ns, int K,
                                          fvec4 acc[4][2], int wm, int wn, int lm, int q8) {
  for (int k0 = 0; k0 < K; k0 += 32) {
    const __bf16* ap = Ms + (k0 >> 5) * 4096 + q8;
    const __bf16* bp = Ns + (k0 >> 5) * 4096 + q8;
    bvec8 a[4], b[2];
#pragma unroll
    for (int i = 0; i < 4; i++) a[i] = *(const bvec8*)(ap + (wm + i * 16 + lm) * 32);
#pragma unroll
    for (int j = 0; j < 2; j++) b[j] = *(const bvec8*)(bp + (wn + j * 16 + lm) * 32);
#pragma unroll
    for (int i = 0; i < 4; i++)
#pragma unroll
      for (int j = 0; j < 2; j++)
        acc[i][j] = __builtin_amdgcn_mfma_f32_16x16x32_bf16(a[i], b[j], acc[i][j], 0, 0, 0);
  }
}

// legacy 4-wave version (pred_kernel only)
__device__ __forceinline__ void gemm128(const __bf16* As, const __bf16* Ws, int K,
                                        fvec4 acc[4][4], int wm, int wn, int lm, int q8) {
  for (int k0 = 0; k0 < K; k0 += 32) {
    const __bf16* ap = As + (k0 >> 5) * 4096 + q8;
    const __bf16* bp = Ws + (k0 >> 5) * 4096 + q8;
    bvec8 a[4], b[4];
#pragma unroll
    for (int i = 0; i < 4; i++) a[i] = *(const bvec8*)(ap + (wm + i * 16 + lm) * 32);
#pragma unroll
    for (int j = 0; j < 4; j++) b[j] = *(const bvec8*)(bp + (wn + j * 16 + lm) * 32);
#pragma unroll
    for (int i = 0; i < 4; i++)
#pragma unroll
      for (int j = 0; j < 4; j++)
        acc[i][j] = __builtin_amdgcn_mfma_f32_16x16x32_bf16(a[i], b[j], acc[i][j], 0, 0, 0);
  }
}

// ---------------- K1: fused 2-layer per-object MLP (512 threads, swapped GEMMs) ----------------
__global__ __launch_bounds__(512) void mlp_kernel(const float* __restrict__ x,
    const __bf16* __restrict__ fw1t, const float* __restrict__ fb1,
    const __bf16* __restrict__ fw2t, const float* __restrict__ fb2,
    __bf16* __restrict__ h0) {
  __shared__ __align__(16) __bf16 smem[32768];
  int efo = blockIdx.y, mt = blockIdx.x;
  int t = threadIdx.x, l = t & 63, w = t >> 6;
  int wm = (w & 1) * 64, wn = (w >> 1) * 32;
  int lm = l & 15, q8 = (l >> 4) * 8, qr = (l >> 4) * 4;
  __bf16* xs = smem;           // [1][128][32]
  __bf16* w1s = smem + 4096;
  __bf16* h1s = smem;          // phase 2: [4][128][32], rows=b, k=DH
  __bf16* w2s = smem + 16384;
  stage_async(fw2t + (size_t)efo * DH_ * DH_, DH_, w2s, DH_);
  stage_async(fw1t + (size_t)efo * DH_ * DIN_, DIN_, w1s, DIN_);
  stage_tile_f32_512(x + ((size_t)efo * B_ + mt * 128) * DIN_, DIN_, xs, DIN_);
  __syncthreads();
  fvec4 zero4 = {0.f, 0.f, 0.f, 0.f};
  fvec4 acc[4][2];
#pragma unroll
  for (int i = 0; i < 4; i++)
#pragma unroll
    for (int j = 0; j < 2; j++) acc[i][j] = zero4;
  gemm128_8(w1s, xs, 32, acc, wm, wn, lm, q8);
  __syncthreads();  // waves done reading xs/w1s
#pragma unroll
  for (int i = 0; i < 4; i++) {
    float4 b4 = *(const float4*)(fb1 + efo * DH_ + wm + i * 16 + qr);
    float br[4] = {b4.x, b4.y, b4.z, b4.w};
#pragma unroll
    for (int j = 0; j < 2; j++) {
      int wc0 = wm + i * 16 + qr, bb = wn + j * 16 + lm;
      bvec4 pk;
#pragma unroll
      for (int r = 0; r < 4; r++) pk[r] = (__bf16)fmaxf(acc[i][j][r] + br[r], 0.f);
      *(bvec4*)(h1s + ((wc0 >> 5) * 128 + bb) * 32 + (wc0 & 31)) = pk;
    }
  }
  __syncthreads();
#pragma unroll
  for (int i = 0; i < 4; i++)
#pragma unroll
    for (int j = 0; j < 2; j++) acc[i][j] = zero4;
  gemm128_8(w2s, h1s, 128, acc, wm, wn, lm, q8);
#pragma unroll
  for (int i = 0; i < 4; i++) {
    float4 b4 = *(const float4*)(fb2 + efo * DH_ + wm + i * 16 + qr);
    float br[4] = {b4.x, b4.y, b4.z, b4.w};
#pragma unroll
    for (int j = 0; j < 2; j++) {
      int wc0 = wm + i * 16 + qr, bb = wn + j * 16 + lm;
      bvec4 pk;
#pragma unroll
      for (int r = 0; r < 4; r++) pk[r] = (__bf16)fmaxf(acc[i][j][r] + br[r], 0.f);
      *(bvec4*)(h0 + ((size_t)efo * B_ + mt * 128 + bb) * DH_ + wc0) = pk;
    }
  }
}

// ---------------- K2: fused q+k+v head-projection (512 threads) ----------------
// h staged once; 3 GEMMs; next weight staged async while previous result stores.
__global__ __launch_bounds__(512) void qkv_kernel(const __bf16* __restrict__ hsrc,
    const __bf16* __restrict__ wqt, const __bf16* __restrict__ wkt,
    const __bf16* __restrict__ wvt, __bf16* __restrict__ qdst,
    __bf16* __restrict__ kdst, __bf16* __restrict__ vdst) {
  __shared__ __align__(16) __bf16 smem[32768];
  int efo = blockIdx.y, mt = blockIdx.x;
  int ef = efo / O_, o = efo - ef * O_;
  int t = threadIdx.x, l = t & 63, w = t >> 6;
  int wm = (w & 1) * 64, wn = (w >> 1) * 32;
  int lm = l & 15, q8 = (l >> 4) * 8, qr = (l >> 4) * 4;
  __bf16* hs = smem;
  __bf16* wsm = smem + 16384;
  stage_async(hsrc + ((size_t)efo * B_ + mt * 128) * DH_, DH_, hs, DH_);
  stage_async(wqt + (size_t)efo * DH_ * DH_, DH_, wsm, DH_);
  fvec4 zero4 = {0.f, 0.f, 0.f, 0.f};
  fvec4 acc[4][2];
  auto zero_acc = [&]() {
#pragma unroll
    for (int i = 0; i < 4; i++)
#pragma unroll
      for (int j = 0; j < 2; j++) acc[i][j] = zero4;
  };
  auto store_head = [&](__bf16* __restrict__ dst) {
#pragma unroll
    for (int i = 0; i < 4; i++)
#pragma unroll
      for (int j = 0; j < 2; j++) {
        int wc0 = wm + i * 16 + qr, bb = wn + j * 16 + lm;
        bvec4 pk;
#pragma unroll
        for (int r = 0; r < 4; r++) pk[r] = (__bf16)acc[i][j][r];
        *(bvec4*)(dst + ((((size_t)ef * H_ + (wc0 >> 5)) * O_ + o) * B_ +
                         mt * 128 + bb) * DK_ + (wc0 & 31)) = pk;
      }
  };
  __syncthreads();
  zero_acc();
  gemm128_8(wsm, hs, 128, acc, wm, wn, lm, q8);
  __syncthreads();  // waves done reading wq
  stage_async(wkt + (size_t)efo * DH_ * DH_, DH_, wsm, DH_);  // in flight during q store
  store_head(qdst);
  __syncthreads();  // drains wk
  zero_acc();
  gemm128_8(wsm, hs, 128, acc, wm, wn, lm, q8);
  __syncthreads();  // waves done reading wk
  stage_async(wvt + (size_t)efo * DH_ * DH_, DH_, wsm, DH_);
  store_head(kdst);
  __syncthreads();  // drains wv
  zero_acc();
  gemm128_8(wsm, hs, 128, acc, wm, wn, lm, q8);
  store_head(vdst);
}

// ---------------- K3: fused scores+softmax+apply; writes attn-out IN PLACE over k ----------------
// Safe: each thread loads its full k slice into regs before any store; blocks
// partition (efh, b) disjointly and out layout == k layout.
__global__ __launch_bounds__(256) void attn_kernel(const __bf16* __restrict__ q,
    __bf16* kv, const __bf16* __restrict__ v) {
  int t = threadIdx.x;
  int g = t >> 2, sub = t & 3;
  int blk = blockIdx.x;
  int bt = blk & 7, efh = blk >> 3;
  int b = bt * 64 + g, d0 = sub * 8;
  size_t base = (size_t)efh * O_ * B_ * DK_ + (size_t)b * DK_ + d0;
  const size_t ostr = (size_t)B_ * DK_;
  bvec8 kr[9], vr[9];
#pragma unroll
  for (int o = 0; o < 9; o++) kr[o] = *(const bvec8*)(kv + base + (size_t)o * ostr);
#pragma unroll
  for (int o = 0; o < 9; o++) vr[o] = *(const bvec8*)(v + base + (size_t)o * ostr);
  const float scale = 0.17677669529663687f;  // 1/sqrt(32)
#pragma unroll 1
  for (int oq = 0; oq < 9; oq++) {
    bvec8 qv = *(const bvec8*)(q + base + (size_t)oq * ostr);
    float qf[8];
#pragma unroll
    for (int j = 0; j < 8; j++) qf[j] = (float)qv[j];
    float lg[9];
#pragma unroll
    for (int ok = 0; ok < 9; ok++) {
      float s = 0.f;
#pragma unroll
      for (int j = 0; j < 8; j++) s += qf[j] * (float)kr[ok][j];
      s += __shfl_xor(s, 1);
      s += __shfl_xor(s, 2);
      lg[ok] = s * scale;
    }
    float mx = lg[0];
#pragma unroll
    for (int ok = 1; ok < 9; ok++) mx = fmaxf(mx, lg[ok]);
    float sum = 0.f;
#pragma unroll
    for (int ok = 0; ok < 9; ok++) { lg[ok] = __expf(lg[ok] - mx); sum += lg[ok]; }
    float inv = 1.f / sum;
    float oacc[8] = {0.f, 0.f, 0.f, 0.f, 0.f, 0.f, 0.f, 0.f};
#pragma unroll
    for (int ok = 0; ok < 9; ok++)
#pragma unroll
      for (int j = 0; j < 8; j++) oacc[j] += lg[ok] * (float)vr[ok][j];
    bvec8 ov;
#pragma unroll
    for (int j = 0; j < 8; j++) ov[j] = (__bf16)(oacc[j] * inv);
    *(bvec8*)(kv + base + (size_t)oq * ostr) = ov;
  }
}

// ---------------- K5: out-proj + residual + post-FC (512 threads; hout aliases resid) ----------------
__global__ __launch_bounds__(512) void proj_kernel(const __bf16* __restrict__ ain,
    const __bf16* __restrict__ wot, const __bf16* __restrict__ pwt,
    const float* __restrict__ pb, const __bf16* resid,
    __bf16* hout) {
  __shared__ __align__(16) __bf16 smem[32768];
  int efo = blockIdx.y, mt = blockIdx.x;
  int ef = efo / O_, o = efo - ef * O_;
  int t = threadIdx.x, l = t & 63, w = t >> 6;
  int wm = (w & 1) * 64, wn = (w >> 1) * 32;
  int lm = l & 15, q8 = (l >> 4) * 8, qr = (l >> 4) * 4;
  __bf16* as2 = smem;          // rows=b, k-panels = head*32
  __bf16* wsm = smem + 16384;
#pragma unroll
  for (int hh = 0; hh < 4; hh++)
    stage_async(ain + ((((size_t)ef * H_ + hh) * O_ + o) * B_ + mt * 128) * DK_, DK_,
                as2 + hh * 4096, DK_);
  stage_async(wot + (size_t)efo * DH_ * DH_, DH_, wsm, DH_);
  __syncthreads();
  fvec4 zero4 = {0.f, 0.f, 0.f, 0.f};
  fvec4 acc[4][2];
#pragma unroll
  for (int i = 0; i < 4; i++)
#pragma unroll
    for (int j = 0; j < 2; j++) acc[i][j] = zero4;
  gemm128_8(wsm, as2, 128, acc, wm, wn, lm, q8);
  // residual add (fp32), flat layout, bvec4 reads; in-place hout==resid safe
#pragma unroll
  for (int i = 0; i < 4; i++)
#pragma unroll
    for (int j = 0; j < 2; j++) {
      int wc0 = wm + i * 16 + qr, bb = wn + j * 16 + lm;
      bvec4 rv = *(const bvec4*)(resid + ((size_t)efo * B_ + mt * 128 + bb) * DH_ + wc0);
#pragma unroll
      for (int r = 0; r < 4; r++) acc[i][j][r] += (float)rv[r];
    }
  __syncthreads();  // waves done reading as2/wot
  stage_async(pwt + (size_t)efo * DH_ * DH_, DH_, wsm, DH_);  // overlaps writeback
#pragma unroll
  for (int i = 0; i < 4; i++)
#pragma unroll
    for (int j = 0; j < 2; j++) {
      int wc0 = wm + i * 16 + qr, bb = wn + j * 16 + lm;
      bvec4 pk;
#pragma unroll
      for (int r = 0; r < 4; r++) pk[r] = (__bf16)acc[i][j][r];
      *(bvec4*)(as2 + ((wc0 >> 5) * 128 + bb) * 32 + (wc0 & 31)) = pk;
    }
  __syncthreads();
#pragma unroll
  for (int i = 0; i < 4; i++)
#pragma unroll
    for (int j = 0; j < 2; j++) acc[i][j] = zero4;
  gemm128_8(wsm, as2, 128, acc, wm, wn, lm, q8);
#pragma unroll
  for (int i = 0; i < 4; i++) {
    float4 b4 = *(const float4*)(pb + efo * DH_ + wm + i * 16 + qr);
    float br[4] = {b4.x, b4.y, b4.z, b4.w};
#pragma unroll
    for (int j = 0; j < 2; j++) {
      int wc0 = wm + i * 16 + qr, bb = wn + j * 16 + lm;
      bvec4 pk;
#pragma unroll
      for (int r = 0; r < 4; r++) pk[r] = (__bf16)fmaxf(acc[i][j][r] + br[r], 0.f);
      *(bvec4*)(hout + ((size_t)efo * B_ + mt * 128 + bb) * DH_ + wc0) = pk;
    }
  }
}

// ---------------- K6: mean-pool over objects ----------------
__global__ __launch_bounds__(256) void pool_kernel(const __bf16* __restrict__ h2,
                                                   __bf16* __restrict__ pooled) {
  size_t idx = ((size_t)blockIdx.x * 256 + threadIdx.x) * 8;
  int ef = (int)(idx >> 16);  // B_*DH_ = 65536 per (e,f)
  int rem = (int)(idx & 65535);
  float accv[8] = {0.f, 0.f, 0.f, 0.f, 0.f, 0.f, 0.f, 0.f};
#pragma unroll
  for (int o = 0; o < 9; o++) {
    bvec8 tv = *(const bvec8*)(h2 + (size_t)(ef * O_ + o) * B_ * DH_ + rem);
#pragma unroll
    for (int j = 0; j < 8; j++) accv[j] += (float)tv[j];
  }
  const float inv9 = 1.f / 9.f;
  bvec8 ov;
#pragma unroll
  for (int j = 0; j < 8; j++) ov[j] = (__bf16)(accv[j] * inv9);
  *(bvec8*)(pooled + idx) = ov;
}

// ---------------- K7: predictor (2 GEMMs fused), fp32 output (256 threads) ----------------
__global__ __launch_bounds__(256) void pred_kernel(const __bf16* __restrict__ pooled,
    const __bf16* __restrict__ pw1t, const float* __restrict__ pb1,
    const __bf16* __restrict__ pw2t, const float* __restrict__ pb2,
    float* __restrict__ out) {
  __shared__ __align__(16) __bf16 smem[32768];
  int ef = blockIdx.y, mt = blockIdx.x;
  int t = threadIdx.x, l = t & 63, w = t >> 6;
  int wm = (w & 1) * 64, wn = (w >> 1) * 64;
  int lm = l & 15, q8 = (l >> 4) * 8, qr = (l >> 4) * 4;
  __bf16* ps = smem;
  __bf16* wsm = smem + 16384;
  stage_tile(pooled + ((size_t)ef * B_ + mt * 128) * DH_, DH_, ps, DH_);
  stage_tile(pw1t + (size_t)ef * DH_ * DH_, DH_, wsm, DH_);
  __syncthreads();
  fvec4 zero4 = {0.f, 0.f, 0.f, 0.f};
  fvec4 acc[4][4];
#pragma unroll
  for (int i = 0; i < 4; i++)
#pragma unroll
    for (int j = 0; j < 4; j++) acc[i][j] = zero4;
  gemm128(ps, wsm, 128, acc, wm, wn, lm, q8);
  __syncthreads();
  float bias[4];
#pragma unroll
  for (int j = 0; j < 4; j++) bias[j] = pb1[ef * DH_ + wn + j * 16 + lm];
#pragma unroll
  for (int i = 0; i < 4; i++)
#pragma unroll
    for (int j = 0; j < 4; j++)
#pragma unroll
      for (int r = 0; r < 4; r++) {
        float vv = fmaxf(acc[i][j][r] + bias[j], 0.f);
        int row = wm + i * 16 + qr + r, col = wn + j * 16 + lm;
        ps[((col >> 5) * 128 + row) * 32 + (col & 31)] = (__bf16)vv;
      }
  // stage pw2t [17][128] (bf16, transposed) zero-padded to [32][128]
  for (int c = threadIdx.x; c < 512; c += 256) {
    int r = c >> 4, cc = (c & 15) << 3;
    uint4 val;
    val.x = val.y = val.z = val.w = 0u;
    if (r < FINAL_)
      val = *(const uint4*)(pw2t + (size_t)ef * FINAL_ * DH_ + r * DH_ + cc);
    *(uint4*)(wsm + ((cc >> 5) * 32 + r) * 32 + (cc & 31)) = val;
  }
  __syncthreads();
  fvec4 acc2[2][2];
#pragma unroll
  for (int i = 0; i < 2; i++)
#pragma unroll
    for (int j = 0; j < 2; j++) acc2[i][j] = zero4;
  for (int k0 = 0; k0 < 128; k0 += 32) {
    bvec8 a2[2], b2[2];
#pragma unroll
    for (int i = 0; i < 2; i++)
      a2[i] = *(const bvec8*)(ps + ((k0 >> 5) * 128 + w * 32 + i * 16 + lm) * 32 + q8);
#pragma unroll
    for (int j = 0; j < 2; j++)
      b2[j] = *(const bvec8*)(wsm + ((k0 >> 5) * 32 + j * 16 + lm) * 32 + q8);
#pragma unroll
    for (int i = 0; i < 2; i++)
#pragma unroll
      for (int j = 0; j < 2; j++)
        acc2[i][j] = __builtin_amdgcn_mfma_f32_16x16x32_bf16(a2[i], b2[j], acc2[i][j], 0, 0, 0);
  }
#pragma unroll
  for (int i = 0; i < 2; i++)
#pragma unroll
    for (int j = 0; j < 2; j++)
#pragma unroll
      for (int r = 0; r < 4; r++) {
        int col = j * 16 + lm;
        if (col < FINAL_) {
          int b = mt * 128 + w * 32 + i * 16 + qr + r;
          out[((size_t)ef * B_ + b) * FINAL_ + col] =
              acc2[i][j][r] + pb2[ef * FINAL_ + col];
        }
      }
}

// ---------------- host ----------------
extern "C" void kernel_launch(void* const* d_in, const int* in_sizes, int n_in,
                              void* d_out, int out_size, void* d_ws, size_t ws_size,
                              hipStream_t stream) {
  (void)in_sizes; (void)n_in; (void)out_size; (void)ws_size;
  const float* x     = (const float*)d_in[0];
  const float* fb1   = (const float*)d_in[2];
  const float* fb2   = (const float*)d_in[4];
  const float* a0_pb = (const float*)d_in[10];
  const float* a1_pb = (const float*)d_in[16];
  const float* pb1   = (const float*)d_in[18];
  const float* pb2   = (const float*)d_in[20];

  __bf16* wsb = (__bf16*)d_ws;
  const size_t SLOT = (size_t)EFO_ * DH_ * DH_;   // 9,437,184 elems
  const size_t ABUF = (size_t)EFO_ * B_ * DH_;    // 37,748,736 elems
  __bf16* s0 = wsb;
  __bf16* s1 = s0 + SLOT;
  __bf16* s2 = s1 + SLOT;
  __bf16* A0 = s2 + SLOT;       // h (in-place through both attention blocks)
  __bf16* A1 = A0 + ABUF;       // q
  __bf16* A2 = A1 + ABUF;       // k, then attn-out (in-place)
  __bf16* A3 = A2 + ABUF;       // v
  // total: 3*SLOT + 4*ABUF = ~342 MiB (< ~445 MiB poisoned workspace)

  auto T = [&](const void* src, __bf16* dst, int R, int C, int batch) {
    dim3 g((C + 63) / 64, (R + 63) / 64, batch);
    transpose_k<<<g, 256, 0, stream>>>((const float*)src, dst, R, C);
  };

  dim3 gg(4, EFO_);

  // MLP
  T(d_in[1], s0, DIN_, DH_, EFO_);
  T(d_in[3], s1, DH_, DH_, EFO_);
  mlp_kernel<<<gg, 512, 0, stream>>>(x, s0, fb1, s1, fb2, A0);

  for (int blkI = 0; blkI < 2; blkI++) {
    int wbase = blkI == 0 ? 5 : 11;
    const float* pb = blkI == 0 ? a0_pb : a1_pb;
    transpose3_k<<<dim3(2, 2, EFO_ * 3), 256, 0, stream>>>(
        (const float*)d_in[wbase], (const float*)d_in[wbase + 1],
        (const float*)d_in[wbase + 2], s0, s1, s2);
    qkv_kernel<<<gg, 512, 0, stream>>>(A0, s0, s1, s2, A1, A2, A3);
    attn_kernel<<<2048, 256, 0, stream>>>(A1, A2, A3);  // attn-out over k
    transpose2_k<<<dim3(2, 2, EFO_ * 2), 256, 0, stream>>>(
        (const float*)d_in[wbase + 3], (const float*)d_in[wbase + 4], s0, s1);
    proj_kernel<<<gg, 512, 0, stream>>>(A2, s0, s1, pb, A0, A0);  // in-place h
  }

  // pool + predictor
  T(d_in[17], s0, DH_, DH_, EF_);
  T(d_in[19], s1, DH_, FINAL_, EF_);
  pool_kernel<<<2048, 256, 0, stream>>>(A0, s2);
  pred_kernel<<<dim3(4, EF_), 256, 0, stream>>>(s2, s0, pb1, s1, pb2,
                                                (float*)d_out);
}

// Round 3
// 897.359 us; speedup vs baseline: 1.4906x; 1.1298x over previous
//
#include <hip/hip_runtime.h>
#include <hip/hip_bf16.h>

typedef __bf16 bvec8 __attribute__((ext_vector_type(8)));
typedef __bf16 bvec4 __attribute__((ext_vector_type(4)));
typedef float fvec4 __attribute__((ext_vector_type(4)));

#define E_ 4
#define F_ 16
#define O_ 9
#define B_ 512
#define DIN_ 32
#define H_ 4
#define DK_ 32
#define DH_ 128
#define FINAL_ 17
#define EF_ 64
#define EFO_ 576

// ---------------- transpose+downcast (pw2 only now) ----------------
__global__ __launch_bounds__(256) void transpose_k(const float* __restrict__ in,
                                                   __bf16* __restrict__ out, int R, int C) {
  __shared__ float tile[64 * 65];
  int r0 = blockIdx.y * 64, c0 = blockIdx.x * 64;
  const float* src = in + (size_t)blockIdx.z * R * C;
  __bf16* dst = out + (size_t)blockIdx.z * R * C;
  for (int idx = threadIdx.x; idx < 4096; idx += 256) {
    int r = idx >> 6, c = idx & 63;
    if ((r0 + r) < R && (c0 + c) < C)
      tile[r * 65 + c] = src[(size_t)(r0 + r) * C + (c0 + c)];
  }
  __syncthreads();
  for (int idx = threadIdx.x; idx < 4096; idx += 256) {
    int c = idx >> 6, r = idx & 63;
    if ((r0 + r) < R && (c0 + c) < C)
      dst[(size_t)(c0 + c) * R + (r0 + r)] = (__bf16)tile[r * 65 + c];
  }
}

// ---------------- XCD-aware block decode for 1D grid of 2304 (=576 efo x 4 mt) ----
// Consecutive block ids round-robin XCDs; this mapping puts all 4 mt-tiles of an
// efo on ONE XCD so the shared fp32 weight is 1 HBM read + 3 L2 hits.
__device__ __forceinline__ void decode_id(int& efo, int& mt) {
  int id = blockIdx.x;
  int xcd = id & 7, wi = id >> 3;       // 288 blocks per xcd
  efo = xcd * 72 + (wi >> 2);           // 72 efos per xcd
  mt = wi & 3;
}

// ---------------- staging helpers ----------------
// LDS tile layout: panels [K/32][128 rows][32 k], fragments read as contiguous 16B.

// Async global->LDS staging (width 16), bf16 source already in panel-row layout.
__device__ __forceinline__ void stage_async(const __bf16* __restrict__ g, int ldg,
                                            __bf16* s, int cols) {
  int lane = threadIdx.x & 63, w = threadIdx.x >> 6;
  int nwb = cols >> 2;  // wave-blocks of 1KB
  for (int wb = w; wb < nwb; wb += 8) {
    int p = wb >> 3, r0 = (wb & 7) << 4;
    int r = r0 + (lane >> 2), c = lane & 3;
    const __bf16* gp = g + (size_t)r * ldg + p * 32 + c * 8;
    __bf16* lp = s + (((p << 7) + r0) << 5);  // wave-uniform
    __builtin_amdgcn_global_load_lds((const __attribute__((address_space(1))) void*)gp,
                                     (__attribute__((address_space(3))) void*)lp,
                                     16, 0, 0);
  }
}

// Direct transposed staging of native fp32 weight w[K][128] -> bf16 panels
// [K/32][128 j][32 k]. Split into load (issue early) / write (after overlap work).
// Lane map: slot=l>>4, j=wave*16+(l&15): global reads are 64B-segment coalesced;
// ds_write_b128 at dword j*16+slot*4 covers all 32 banks evenly (conflict-free).
template <int K>
__device__ __forceinline__ void stage_wT_load(const float* __restrict__ g,
                                              float regs[][8]) {
  int t = threadIdx.x, l = t & 63;
  int slot = l >> 4;
  int j = (t >> 6) * 16 + (l & 15);
#pragma unroll
  for (int gi = 0; gi < K / 32; gi++) {
    int i0 = (4 * gi + slot) * 8;
#pragma unroll
    for (int r = 0; r < 8; r++)
      regs[gi][r] = g[(size_t)(i0 + r) * 128 + j];
  }
}
template <int K>
__device__ __forceinline__ void stage_wT_write(const float regs[][8], __bf16* s) {
  int t = threadIdx.x, l = t & 63;
  int slot = l >> 4;
  int j = (t >> 6) * 16 + (l & 15);
#pragma unroll
  for (int gi = 0; gi < K / 32; gi++) {
    bvec8 bv;
#pragma unroll
    for (int r = 0; r < 8; r++) bv[r] = (__bf16)regs[gi][r];
    *(bvec8*)(s + (gi * 128 + j) * 32 + slot * 8) = bv;
  }
}

// 256-thread variant (pred): loops j over two halves.
__device__ __forceinline__ void stage_wT_256(const float* __restrict__ g, __bf16* s) {
  int t = threadIdx.x, l = t & 63;
  int slot = l >> 4;
  int jb = (t >> 6) * 16 + (l & 15);  // 0..63
#pragma unroll
  for (int jh = 0; jh < 2; jh++) {
    int j = jh * 64 + jb;
    float regs[4][8];
#pragma unroll
    for (int gi = 0; gi < 4; gi++)
#pragma unroll
      for (int r = 0; r < 8; r++)
        regs[gi][r] = g[(size_t)((4 * gi + slot) * 8 + r) * 128 + j];
#pragma unroll
    for (int gi = 0; gi < 4; gi++) {
      bvec8 bv;
#pragma unroll
      for (int r = 0; r < 8; r++) bv[r] = (__bf16)regs[gi][r];
      *(bvec8*)(s + (gi * 128 + j) * 32 + slot * 8) = bv;
    }
  }
}

// fp32 global source -> bf16 LDS tile (activation x), 512-thread blocks
__device__ __forceinline__ void stage_tile_f32_512(const float* __restrict__ g, int ldg,
                                                   __bf16* s, int cols) {
  int cpr = cols >> 3;
  int nch = 128 * cpr;
  for (int c = threadIdx.x; c < nch; c += 512) {
    int r = c / cpr;
    int cc = (c - r * cpr) << 3;
    const float* gp = g + (size_t)r * ldg + cc;
    float4 f0 = *(const float4*)gp;
    float4 f1 = *(const float4*)(gp + 4);
    bvec8 bv;
    bv[0] = (__bf16)f0.x; bv[1] = (__bf16)f0.y; bv[2] = (__bf16)f0.z; bv[3] = (__bf16)f0.w;
    bv[4] = (__bf16)f1.x; bv[5] = (__bf16)f1.y; bv[6] = (__bf16)f1.z; bv[7] = (__bf16)f1.w;
    *(bvec8*)(s + ((cc >> 5) * 128 + r) * 32 + (cc & 31)) = bv;
  }
}

// legacy 256-thread reg-staging (pred_kernel pooled input)
__device__ __forceinline__ void stage_tile(const __bf16* __restrict__ g, int ldg,
                                           __bf16* s, int cols) {
  int cpr = cols >> 3;
  int nch = 128 * cpr;
  for (int c = threadIdx.x; c < nch; c += 256) {
    int r = c / cpr;
    int cc = (c - r * cpr) << 3;
    *(uint4*)(s + ((cc >> 5) * 128 + r) * 32 + (cc & 31)) =
        *(const uint4*)(g + (size_t)r * ldg + cc);
  }
}

// ---------------- GEMM cores ----------------
// 8-wave, SWAPPED convention: first operand = M (weight cols), second = N (batch rows).
__device__ __forceinline__ void gemm128_8(const __bf16* Ms, const __bf16* Ns, int K,
                                          fvec4 acc[4][2], int wm, int wn, int lm, int q8) {
  for (int k0 = 0; k0 < K; k0 += 32) {
    const __bf16* ap = Ms + (k0 >> 5) * 4096 + q8;
    const __bf16* bp = Ns + (k0 >> 5) * 4096 + q8;
    bvec8 a[4], b[2];
#pragma unroll
    for (int i = 0; i < 4; i++) a[i] = *(const bvec8*)(ap + (wm + i * 16 + lm) * 32);
#pragma unroll
    for (int j = 0; j < 2; j++) b[j] = *(const bvec8*)(bp + (wn + j * 16 + lm) * 32);
#pragma unroll
    for (int i = 0; i < 4; i++)
#pragma unroll
      for (int j = 0; j < 2; j++)
        acc[i][j] = __builtin_amdgcn_mfma_f32_16x16x32_bf16(a[i], b[j], acc[i][j], 0, 0, 0);
  }
}

// legacy 4-wave version (pred_kernel only)
__device__ __forceinline__ void gemm128(const __bf16* As, const __bf16* Ws, int K,
                                        fvec4 acc[4][4], int wm, int wn, int lm, int q8) {
  for (int k0 = 0; k0 < K; k0 += 32) {
    const __bf16* ap = As + (k0 >> 5) * 4096 + q8;
    const __bf16* bp = Ws + (k0 >> 5) * 4096 + q8;
    bvec8 a[4], b[4];
#pragma unroll
    for (int i = 0; i < 4; i++) a[i] = *(const bvec8*)(ap + (wm + i * 16 + lm) * 32);
#pragma unroll
    for (int j = 0; j < 4; j++) b[j] = *(const bvec8*)(bp + (wn + j * 16 + lm) * 32);
#pragma unroll
    for (int i = 0; i < 4; i++)
#pragma unroll
      for (int j = 0; j < 4; j++)
        acc[i][j] = __builtin_amdgcn_mfma_f32_16x16x32_bf16(a[i], b[j], acc[i][j], 0, 0, 0);
  }
}

// ---------------- K1: fused 2-layer per-object MLP (512 threads) ----------------
__global__ __launch_bounds__(512) void mlp_kernel(const float* __restrict__ x,
    const float* __restrict__ fw1, const float* __restrict__ fb1,
    const float* __restrict__ fw2, const float* __restrict__ fb2,
    __bf16* __restrict__ h0) {
  __shared__ __align__(16) __bf16 smem[32768];
  int efo, mt;
  decode_id(efo, mt);
  int t = threadIdx.x, l = t & 63, w = t >> 6;
  int wm = (w & 1) * 64, wn = (w >> 1) * 32;
  int lm = l & 15, q8 = (l >> 4) * 8, qr = (l >> 4) * 4;
  __bf16* xs = smem;           // [1][128][32]
  __bf16* w1s = smem + 4096;
  __bf16* h1s = smem;          // phase 2: [4][128][32], rows=b, k=DH
  __bf16* w2s = smem + 16384;
  float r1[1][8], r2[4][8];
  stage_wT_load<32>(fw1 + (size_t)efo * DH_ * DIN_, r1);
  stage_wT_load<128>(fw2 + (size_t)efo * DH_ * DH_, r2);
  stage_tile_f32_512(x + ((size_t)efo * B_ + mt * 128) * DIN_, DIN_, xs, DIN_);
  stage_wT_write<32>(r1, w1s);
  stage_wT_write<128>(r2, w2s);
  __syncthreads();
  fvec4 zero4 = {0.f, 0.f, 0.f, 0.f};
  fvec4 acc[4][2];
#pragma unroll
  for (int i = 0; i < 4; i++)
#pragma unroll
    for (int j = 0; j < 2; j++) acc[i][j] = zero4;
  gemm128_8(w1s, xs, 32, acc, wm, wn, lm, q8);
  __syncthreads();  // waves done reading xs/w1s
#pragma unroll
  for (int i = 0; i < 4; i++) {
    float4 b4 = *(const float4*)(fb1 + efo * DH_ + wm + i * 16 + qr);
    float br[4] = {b4.x, b4.y, b4.z, b4.w};
#pragma unroll
    for (int j = 0; j < 2; j++) {
      int wc0 = wm + i * 16 + qr, bb = wn + j * 16 + lm;
      bvec4 pk;
#pragma unroll
      for (int r = 0; r < 4; r++) pk[r] = (__bf16)fmaxf(acc[i][j][r] + br[r], 0.f);
      *(bvec4*)(h1s + ((wc0 >> 5) * 128 + bb) * 32 + (wc0 & 31)) = pk;
    }
  }
  __syncthreads();
#pragma unroll
  for (int i = 0; i < 4; i++)
#pragma unroll
    for (int j = 0; j < 2; j++) acc[i][j] = zero4;
  gemm128_8(w2s, h1s, 128, acc, wm, wn, lm, q8);
#pragma unroll
  for (int i = 0; i < 4; i++) {
    float4 b4 = *(const float4*)(fb2 + efo * DH_ + wm + i * 16 + qr);
    float br[4] = {b4.x, b4.y, b4.z, b4.w};
#pragma unroll
    for (int j = 0; j < 2; j++) {
      int wc0 = wm + i * 16 + qr, bb = wn + j * 16 + lm;
      bvec4 pk;
#pragma unroll
      for (int r = 0; r < 4; r++) pk[r] = (__bf16)fmaxf(acc[i][j][r] + br[r], 0.f);
      *(bvec4*)(h0 + ((size_t)efo * B_ + mt * 128 + bb) * DH_ + wc0) = pk;
    }
  }
}

// ---------------- K2: fused q+k+v head-projection (512 threads) ----------------
__global__ __launch_bounds__(512) void qkv_kernel(const __bf16* __restrict__ hsrc,
    const float* __restrict__ wq, const float* __restrict__ wk,
    const float* __restrict__ wv, __bf16* __restrict__ qdst,
    __bf16* __restrict__ kdst, __bf16* __restrict__ vdst) {
  __shared__ __align__(16) __bf16 smem[32768];
  int efo, mt;
  decode_id(efo, mt);
  int ef = efo / O_, o = efo - ef * O_;
  int t = threadIdx.x, l = t & 63, w = t >> 6;
  int wm = (w & 1) * 64, wn = (w >> 1) * 32;
  int lm = l & 15, q8 = (l >> 4) * 8, qr = (l >> 4) * 4;
  __bf16* hs = smem;
  __bf16* wsm = smem + 16384;
  size_t wofs = (size_t)efo * DH_ * DH_;
  stage_async(hsrc + ((size_t)efo * B_ + mt * 128) * DH_, DH_, hs, DH_);
  float rw[4][8];
  stage_wT_load<128>(wq + wofs, rw);
  stage_wT_write<128>(rw, wsm);
  fvec4 zero4 = {0.f, 0.f, 0.f, 0.f};
  fvec4 acc[4][2];
  auto zero_acc = [&]() {
#pragma unroll
    for (int i = 0; i < 4; i++)
#pragma unroll
      for (int j = 0; j < 2; j++) acc[i][j] = zero4;
  };
  auto store_head = [&](__bf16* __restrict__ dst) {
#pragma unroll
    for (int i = 0; i < 4; i++)
#pragma unroll
      for (int j = 0; j < 2; j++) {
        int wc0 = wm + i * 16 + qr, bb = wn + j * 16 + lm;
        bvec4 pk;
#pragma unroll
        for (int r = 0; r < 4; r++) pk[r] = (__bf16)acc[i][j][r];
        *(bvec4*)(dst + ((((size_t)ef * H_ + (wc0 >> 5)) * O_ + o) * B_ +
                         mt * 128 + bb) * DK_ + (wc0 & 31)) = pk;
      }
  };
  __syncthreads();
  zero_acc();
  gemm128_8(wsm, hs, 128, acc, wm, wn, lm, q8);
  __syncthreads();  // waves done reading wq panels
  stage_wT_load<128>(wk + wofs, rw);  // loads in flight during q store
  store_head(qdst);
  stage_wT_write<128>(rw, wsm);
  __syncthreads();
  zero_acc();
  gemm128_8(wsm, hs, 128, acc, wm, wn, lm, q8);
  __syncthreads();  // waves done reading wk panels
  stage_wT_load<128>(wv + wofs, rw);
  store_head(kdst);
  stage_wT_write<128>(rw, wsm);
  __syncthreads();
  zero_acc();
  gemm128_8(wsm, hs, 128, acc, wm, wn, lm, q8);
  store_head(vdst);
}

// ---------------- K3: fused scores+softmax+apply; writes attn-out IN PLACE over k ----------------
__global__ __launch_bounds__(256) void attn_kernel(const __bf16* __restrict__ q,
    __bf16* kv, const __bf16* __restrict__ v) {
  int t = threadIdx.x;
  int g = t >> 2, sub = t & 3;
  int blk = blockIdx.x;
  int bt = blk & 7, efh = blk >> 3;
  int b = bt * 64 + g, d0 = sub * 8;
  size_t base = (size_t)efh * O_ * B_ * DK_ + (size_t)b * DK_ + d0;
  const size_t ostr = (size_t)B_ * DK_;
  bvec8 kr[9], vr[9];
#pragma unroll
  for (int o = 0; o < 9; o++) kr[o] = *(const bvec8*)(kv + base + (size_t)o * ostr);
#pragma unroll
  for (int o = 0; o < 9; o++) vr[o] = *(const bvec8*)(v + base + (size_t)o * ostr);
  const float scale = 0.17677669529663687f;  // 1/sqrt(32)
#pragma unroll 1
  for (int oq = 0; oq < 9; oq++) {
    bvec8 qv = *(const bvec8*)(q + base + (size_t)oq * ostr);
    float qf[8];
#pragma unroll
    for (int j = 0; j < 8; j++) qf[j] = (float)qv[j];
    float lg[9];
#pragma unroll
    for (int ok = 0; ok < 9; ok++) {
      float s = 0.f;
#pragma unroll
      for (int j = 0; j < 8; j++) s += qf[j] * (float)kr[ok][j];
      s += __shfl_xor(s, 1);
      s += __shfl_xor(s, 2);
      lg[ok] = s * scale;
    }
    float mx = lg[0];
#pragma unroll
    for (int ok = 1; ok < 9; ok++) mx = fmaxf(mx, lg[ok]);
    float sum = 0.f;
#pragma unroll
    for (int ok = 0; ok < 9; ok++) { lg[ok] = __expf(lg[ok] - mx); sum += lg[ok]; }
    float inv = 1.f / sum;
    float oacc[8] = {0.f, 0.f, 0.f, 0.f, 0.f, 0.f, 0.f, 0.f};
#pragma unroll
    for (int ok = 0; ok < 9; ok++)
#pragma unroll
      for (int j = 0; j < 8; j++) oacc[j] += lg[ok] * (float)vr[ok][j];
    bvec8 ov;
#pragma unroll
    for (int j = 0; j < 8; j++) ov[j] = (__bf16)(oacc[j] * inv);
    *(bvec8*)(kv + base + (size_t)oq * ostr) = ov;
  }
}

// ---------------- K5: out-proj + residual + post-FC (512 threads; hout aliases resid) ----------------
__global__ __launch_bounds__(512) void proj_kernel(const __bf16* __restrict__ ain,
    const float* __restrict__ wo, const float* __restrict__ pw,
    const float* __restrict__ pb, const __bf16* resid,
    __bf16* hout) {
  __shared__ __align__(16) __bf16 smem[32768];
  int efo, mt;
  decode_id(efo, mt);
  int ef = efo / O_, o = efo - ef * O_;
  int t = threadIdx.x, l = t & 63, w = t >> 6;
  int wm = (w & 1) * 64, wn = (w >> 1) * 32;
  int lm = l & 15, q8 = (l >> 4) * 8, qr = (l >> 4) * 4;
  __bf16* as2 = smem;          // rows=b, k-panels = head*32
  __bf16* wsm = smem + 16384;
  size_t wofs = (size_t)efo * DH_ * DH_;
#pragma unroll
  for (int hh = 0; hh < 4; hh++)
    stage_async(ain + ((((size_t)ef * H_ + hh) * O_ + o) * B_ + mt * 128) * DK_, DK_,
                as2 + hh * 4096, DK_);
  float rw[4][8];
  stage_wT_load<128>(wo + wofs, rw);
  stage_wT_write<128>(rw, wsm);
  __syncthreads();
  fvec4 zero4 = {0.f, 0.f, 0.f, 0.f};
  fvec4 acc[4][2];
#pragma unroll
  for (int i = 0; i < 4; i++)
#pragma unroll
    for (int j = 0; j < 2; j++) acc[i][j] = zero4;
  gemm128_8(wsm, as2, 128, acc, wm, wn, lm, q8);
  // residual add (fp32), flat layout; in-place hout==resid safe
#pragma unroll
  for (int i = 0; i < 4; i++)
#pragma unroll
    for (int j = 0; j < 2; j++) {
      int wc0 = wm + i * 16 + qr, bb = wn + j * 16 + lm;
      bvec4 rv = *(const bvec4*)(resid + ((size_t)efo * B_ + mt * 128 + bb) * DH_ + wc0);
#pragma unroll
      for (int r = 0; r < 4; r++) acc[i][j][r] += (float)rv[r];
    }
  __syncthreads();  // waves done reading as2/wo panels
  stage_wT_load<128>(pw + wofs, rw);  // loads overlap the LDS writeback
#pragma unroll
  for (int i = 0; i < 4; i++)
#pragma unroll
    for (int j = 0; j < 2; j++) {
      int wc0 = wm + i * 16 + qr, bb = wn + j * 16 + lm;
      bvec4 pk;
#pragma unroll
      for (int r = 0; r < 4; r++) pk[r] = (__bf16)acc[i][j][r];
      *(bvec4*)(as2 + ((wc0 >> 5) * 128 + bb) * 32 + (wc0 & 31)) = pk;
    }
  stage_wT_write<128>(rw, wsm);
  __syncthreads();
#pragma unroll
  for (int i = 0; i < 4; i++)
#pragma unroll
    for (int j = 0; j < 2; j++) acc[i][j] = zero4;
  gemm128_8(wsm, as2, 128, acc, wm, wn, lm, q8);
#pragma unroll
  for (int i = 0; i < 4; i++) {
    float4 b4 = *(const float4*)(pb + efo * DH_ + wm + i * 16 + qr);
    float br[4] = {b4.x, b4.y, b4.z, b4.w};
#pragma unroll
    for (int j = 0; j < 2; j++) {
      int wc0 = wm + i * 16 + qr, bb = wn + j * 16 + lm;
      bvec4 pk;
#pragma unroll
      for (int r = 0; r < 4; r++) pk[r] = (__bf16)fmaxf(acc[i][j][r] + br[r], 0.f);
      *(bvec4*)(hout + ((size_t)efo * B_ + mt * 128 + bb) * DH_ + wc0) = pk;
    }
  }
}

// ---------------- K6: mean-pool over objects ----------------
__global__ __launch_bounds__(256) void pool_kernel(const __bf16* __restrict__ h2,
                                                   __bf16* __restrict__ pooled) {
  size_t idx = ((size_t)blockIdx.x * 256 + threadIdx.x) * 8;
  int ef = (int)(idx >> 16);  // B_*DH_ = 65536 per (e,f)
  int rem = (int)(idx & 65535);
  float accv[8] = {0.f, 0.f, 0.f, 0.f, 0.f, 0.f, 0.f, 0.f};
#pragma unroll
  for (int o = 0; o < 9; o++) {
    bvec8 tv = *(const bvec8*)(h2 + (size_t)(ef * O_ + o) * B_ * DH_ + rem);
#pragma unroll
    for (int j = 0; j < 8; j++) accv[j] += (float)tv[j];
  }
  const float inv9 = 1.f / 9.f;
  bvec8 ov;
#pragma unroll
  for (int j = 0; j < 8; j++) ov[j] = (__bf16)(accv[j] * inv9);
  *(bvec8*)(pooled + idx) = ov;
}

// ---------------- K7: predictor (2 GEMMs fused), fp32 output (256 threads) ----------------
__global__ __launch_bounds__(256) void pred_kernel(const __bf16* __restrict__ pooled,
    const float* __restrict__ pw1, const float* __restrict__ pb1,
    const __bf16* __restrict__ pw2t, const float* __restrict__ pb2,
    float* __restrict__ out) {
  __shared__ __align__(16) __bf16 smem[32768];
  int ef = blockIdx.y, mt = blockIdx.x;
  int t = threadIdx.x, l = t & 63, w = t >> 6;
  int wm = (w & 1) * 64, wn = (w >> 1) * 64;
  int lm = l & 15, q8 = (l >> 4) * 8, qr = (l >> 4) * 4;
  __bf16* ps = smem;
  __bf16* wsm = smem + 16384;
  stage_tile(pooled + ((size_t)ef * B_ + mt * 128) * DH_, DH_, ps, DH_);
  stage_wT_256(pw1 + (size_t)ef * DH_ * DH_, wsm);
  __syncthreads();
  fvec4 zero4 = {0.f, 0.f, 0.f, 0.f};
  fvec4 acc[4][4];
#pragma unroll
  for (int i = 0; i < 4; i++)
#pragma unroll
    for (int j = 0; j < 4; j++) acc[i][j] = zero4;
  gemm128(ps, wsm, 128, acc, wm, wn, lm, q8);
  __syncthreads();
  float bias[4];
#pragma unroll
  for (int j = 0; j < 4; j++) bias[j] = pb1[ef * DH_ + wn + j * 16 + lm];
#pragma unroll
  for (int i = 0; i < 4; i++)
#pragma unroll
    for (int j = 0; j < 4; j++)
#pragma unroll
      for (int r = 0; r < 4; r++) {
        float vv = fmaxf(acc[i][j][r] + bias[j], 0.f);
        int row = wm + i * 16 + qr + r, col = wn + j * 16 + lm;
        ps[((col >> 5) * 128 + row) * 32 + (col & 31)] = (__bf16)vv;
      }
  // stage pw2t [17][128] (bf16, transposed) zero-padded to [32][128]
  for (int c = threadIdx.x; c < 512; c += 256) {
    int r = c >> 4, cc = (c & 15) << 3;
    uint4 val;
    val.x = val.y = val.z = val.w = 0u;
    if (r < FINAL_)
      val = *(const uint4*)(pw2t + (size_t)ef * FINAL_ * DH_ + r * DH_ + cc);
    *(uint4*)(wsm + ((cc >> 5) * 32 + r) * 32 + (cc & 31)) = val;
  }
  __syncthreads();
  fvec4 acc2[2][2];
#pragma unroll
  for (int i = 0; i < 2; i++)
#pragma unroll
    for (int j = 0; j < 2; j++) acc2[i][j] = zero4;
  for (int k0 = 0; k0 < 128; k0 += 32) {
    bvec8 a2[2], b2[2];
#pragma unroll
    for (int i = 0; i < 2; i++)
      a2[i] = *(const bvec8*)(ps + ((k0 >> 5) * 128 + w * 32 + i * 16 + lm) * 32 + q8);
#pragma unroll
    for (int j = 0; j < 2; j++)
      b2[j] = *(const bvec8*)(wsm + ((k0 >> 5) * 32 + j * 16 + lm) * 32 + q8);
#pragma unroll
    for (int i = 0; i < 2; i++)
#pragma unroll
      for (int j = 0; j < 2; j++)
        acc2[i][j] = __builtin_amdgcn_mfma_f32_16x16x32_bf16(a2[i], b2[j], acc2[i][j], 0, 0, 0);
  }
#pragma unroll
  for (int i = 0; i < 2; i++)
#pragma unroll
    for (int j = 0; j < 2; j++)
#pragma unroll
      for (int r = 0; r < 4; r++) {
        int col = j * 16 + lm;
        if (col < FINAL_) {
          int b = mt * 128 + w * 32 + i * 16 + qr + r;
          out[((size_t)ef * B_ + b) * FINAL_ + col] =
              acc2[i][j][r] + pb2[ef * FINAL_ + col];
        }
      }
}

// ---------------- host ----------------
extern "C" void kernel_launch(void* const* d_in, const int* in_sizes, int n_in,
                              void* d_out, int out_size, void* d_ws, size_t ws_size,
                              hipStream_t stream) {
  (void)in_sizes; (void)n_in; (void)out_size; (void)ws_size;
  const float* x     = (const float*)d_in[0];
  const float* fw1   = (const float*)d_in[1];
  const float* fb1   = (const float*)d_in[2];
  const float* fw2   = (const float*)d_in[3];
  const float* fb2   = (const float*)d_in[4];
  const float* a0_pb = (const float*)d_in[10];
  const float* a1_pb = (const float*)d_in[16];
  const float* pw1   = (const float*)d_in[17];
  const float* pb1   = (const float*)d_in[18];
  const float* pb2   = (const float*)d_in[20];

  __bf16* wsb = (__bf16*)d_ws;
  const size_t SLOT = (size_t)EFO_ * DH_ * DH_;   // 9,437,184 elems
  const size_t ABUF = (size_t)EFO_ * B_ * DH_;    // 37,748,736 elems
  __bf16* s1 = wsb;             // pw2t (small)
  __bf16* s2 = s1 + SLOT;       // pooled
  __bf16* A0 = s2 + SLOT;       // h (in-place through both attention blocks)
  __bf16* A1 = A0 + ABUF;       // q
  __bf16* A2 = A1 + ABUF;       // k, then attn-out (in-place)
  __bf16* A3 = A2 + ABUF;       // v

  // MLP (2304 blocks, XCD-swizzled)
  mlp_kernel<<<2304, 512, 0, stream>>>(x, fw1, fb1, fw2, fb2, A0);

  for (int blkI = 0; blkI < 2; blkI++) {
    int wbase = blkI == 0 ? 5 : 11;
    const float* pb = blkI == 0 ? a0_pb : a1_pb;
    qkv_kernel<<<2304, 512, 0, stream>>>(A0, (const float*)d_in[wbase],
                                         (const float*)d_in[wbase + 1],
                                         (const float*)d_in[wbase + 2], A1, A2, A3);
    attn_kernel<<<2048, 256, 0, stream>>>(A1, A2, A3);  // attn-out over k
    proj_kernel<<<2304, 512, 0, stream>>>(A2, (const float*)d_in[wbase + 3],
                                          (const float*)d_in[wbase + 4], pb, A0, A0);
  }

  // pool + predictor
  {
    dim3 g((FINAL_ + 63) / 64, (DH_ + 63) / 64, EF_);
    transpose_k<<<g, 256, 0, stream>>>((const float*)d_in[19], s1, DH_, FINAL_);
  }
  pool_kernel<<<2048, 256, 0, stream>>>(A0, s2);
  pred_kernel<<<dim3(4, EF_), 256, 0, stream>>>(s2, pw1, pb1, s1, pb2,
                                                (float*)d_out);
}